// Round 9
// baseline (163.992 us; speedup 1.0000x reference)
//
#include <hip/hip_runtime.h>
#include <hip/hip_cooperative_groups.h>
#include <math.h>

namespace cg = cooperative_groups;

#define S_GRID   112
#define BATCH_N  64
#define NBOX     100
#define SS       (S_GRID * S_GRID)       // 12544 cells per image
#define NCELLS   (BATCH_N * SS)          // 802816
#define NF4      (NCELLS * 5)            // 4,014,080 float4s in pred
#define CELLSZ   (1.0f / (float)S_GRID)
#define BLK      256
#define GRID     1024
#define STRIDE   (GRID * BLK)            // 262144
#define FULL     15                      // NF4 / STRIDE
#define REM      (NF4 - FULL * STRIDE)   // 81920

// ---------- device helpers ----------

__device__ __forceinline__ float iou_fn(float px, float py, float pw, float ph,
                                        float gx, float gy, float gw, float gh) {
    // matches reference _iou (eps = 1e-6)
    float px1 = px - pw * 0.5f, px2 = px + pw * 0.5f;
    float py1 = py - ph * 0.5f, py2 = py + ph * 0.5f;
    float gx1 = gx - gw * 0.5f, gx2 = gx + gw * 0.5f;
    float gy1 = gy - gh * 0.5f, gy2 = gy + gh * 0.5f;
    float iw = fmaxf(fminf(px2, gx2) - fmaxf(px1, gx1), 0.f);
    float ih = fmaxf(fminf(py2, gy2) - fmaxf(py1, gy1), 0.f);
    float inter = iw * ih;
    float ap = fmaxf(px2 - px1, 0.f) * fmaxf(py2 - py1, 0.f);
    float ag = fmaxf(gx2 - gx1, 0.f) * fmaxf(gy2 - gy1, 0.f);
    float uni = ap + ag - inter;
    return inter / (uni + 1e-6f);
}

__device__ __forceinline__ float ciou_fn(float px, float py, float pw, float ph,
                                         float gx, float gy, float gw, float gh) {
    // matches reference _ciou (eps = 1e-7)
    const float eps = 1e-7f;
    float px1 = px - pw * 0.5f, px2 = px + pw * 0.5f;
    float py1 = py - ph * 0.5f, py2 = py + ph * 0.5f;
    float gx1 = gx - gw * 0.5f, gx2 = gx + gw * 0.5f;
    float gy1 = gy - gh * 0.5f, gy2 = gy + gh * 0.5f;
    float iw = fmaxf(fminf(px2, gx2) - fmaxf(px1, gx1), 0.f);
    float ih = fmaxf(fminf(py2, gy2) - fmaxf(py1, gy1), 0.f);
    float inter = iw * ih;
    float ap = fmaxf(px2 - px1, 0.f) * fmaxf(py2 - py1, 0.f);
    float ag = fmaxf(gx2 - gx1, 0.f) * fmaxf(gy2 - gy1, 0.f);
    float uni = ap + ag - inter;
    float iou = inter / (uni + eps);
    float dx = px - gx, dy = py - gy;
    float rho2 = dx * dx + dy * dy;
    float cw = fmaxf(px2, gx2) - fminf(px1, gx1);
    float ch = fmaxf(py2, gy2) - fminf(py1, gy1);
    float c2 = cw * cw + ch * ch + eps;
    float dv = atanf(gw / (gh + eps)) - atanf(pw / (ph + eps));
    float v = 0.40528473456935109f * dv * dv;   // 4/pi^2
    float alpha = v / (1.f - iou + v + eps);
    return 1.f - iou + rho2 / c2 + alpha * v;
}

__device__ __forceinline__ float focal_fn(float logit, float t) {
    float bce = fmaxf(logit, 0.f) - logit * t + log1pf(expf(-fabsf(logit)));
    float p = 1.f / (1.f + expf(-logit));
    float p_t = t * p + (1.f - t) * (1.f - p);
    float a_t = t * 0.25f + (1.f - t) * 0.75f;
    float om = 1.f - p_t;
    return a_t * om * om * bce;
}

// ---------- single cooperative kernel ----------
// Phase A: all blocks stream pred (float4) for the 0.1*conf^2 noobj sum.
// Phase B: blocks 0..63 handle image bid's hit cells (winner scan, CIoU,
//          focal, obj MSE, minus the stream's over-count).
// grid.sync(); block 0 sums the 1024 partials in fixed order -> out.
// No workspace state carried across calls: partials fully rewritten, no counter.

__global__ __launch_bounds__(BLK, 4) void fused_kernel(const float* __restrict__ pred,
                                                       const float* __restrict__ tgt,
                                                       float* __restrict__ partial,
                                                       float* __restrict__ out) {
    __shared__ int      s_cell[NBOX];
    __shared__ float4   s_box[NBOX];
    __shared__ unsigned s_cbit[NBOX];
    __shared__ float    sred[BLK / 64];

    const int bid = blockIdx.x, tid = threadIdx.x;
    const int gid = bid * BLK + tid;

    // ---- table build for hit blocks (block-uniform branch) ----
    if (bid < BATCH_N) {
        if (tid < NBOX) {
            const float* t = tgt + ((size_t)bid * NBOX + tid) * 5;
            float t0 = t[0], cx = t[1], cy = t[2], w = t[3], h = t[4];
            int cellid = -1; unsigned cb = 0u;
            if (t0 >= 0.f) {
                int cls = min(max((int)t0, 0), 9);
                int col = min(max((int)(cx * (float)S_GRID), 0), S_GRID - 1);
                int row = min(max((int)(cy * (float)S_GRID), 0), S_GRID - 1);
                cellid = row * S_GRID + col;
                cb = 1u << cls;
            }
            s_cell[tid] = cellid;
            s_box[tid]  = make_float4(cx, cy, w, h);
            s_cbit[tid] = cb;
        }
        __syncthreads();
    }

    // ---- phase A: stream noobj conf^2 ----
    const float4* p4 = (const float4*)pred;
    float sacc = 0.f;
    int r = gid % 5;
#pragma unroll
    for (int j = 0; j < FULL; ++j) {
        float4 v = p4[gid + j * STRIDE];
        if (r == 1) sacc += v.x * v.x;     // conf0 (float 4 of cell)
        if (r == 2) sacc += v.y * v.y;     // conf1 (float 9 of cell)
        r += 4; if (r >= 5) r -= 5;        // STRIDE % 5 == 4
    }
    if (gid < REM) {
        float4 v = p4[gid + FULL * STRIDE];
        if (r == 1) sacc += v.x * v.x;
        if (r == 2) sacc += v.y * v.y;
    }
    float acc = 0.1f * sacc;

    // ---- phase B: hit cells for image bid (blocks 0..63) ----
    if (bid < BATCH_N) {
        int mycell = (tid < NBOX) ? s_cell[tid] : -1;
        bool claim = (mycell >= 0);
        if (claim) {                      // owner = smallest box index for this cell
            for (int j = 0; j < tid; ++j)
                if (s_cell[j] == mycell) { claim = false; break; }
        }
        if (claim) {
            const int rc = mycell;
            const float colf = (float)(rc % S_GRID);
            const float rowf = (float)(rc / S_GRID);
            const float* P = pred + ((size_t)bid * SS + rc) * 20;

            float p0 = P[0], p1 = P[1], p2 = P[2], p3 = P[3], conf0 = P[4];
            float p5 = P[5], p6 = P[6], p7 = P[7], p8 = P[8], conf1 = P[9];

            float dx0 = (p0 + colf) * CELLSZ, dy0 = (p1 + rowf) * CELLSZ;
            float dx1 = (p5 + colf) * CELLSZ, dy1 = (p6 + rowf) * CELLSZ;

            unsigned mask = 0u; float bestv = -1.f; int jwin = 0, bj = 0;
            for (int j = 0; j < NBOX; ++j) {
                if (s_cell[j] == rc) {
                    mask |= s_cbit[j];
                    float4 g = s_box[j];
                    float i0 = iou_fn(dx0, dy0, p2, p3, g.x, g.y, g.z, g.w);
                    float i1 = iou_fn(dx1, dy1, p7, p8, g.x, g.y, g.z, g.w);
                    float b = fmaxf(i0, i1);
                    if (b > bestv) { bestv = b; jwin = j; bj = (i0 >= i1) ? 0 : 1; }
                }
            }

            float4 g = s_box[jwin];
            float best_iou = bestv;

            float rx = bj ? p5 : p0;
            float ry = bj ? p6 : p1;
            float rw = bj ? p7 : p2;
            float rh = bj ? p8 : p3;
            float rconf = bj ? conf1 : conf0;
            float oconf = bj ? conf0 : conf1;

            float pax = (rx + colf) * CELLSZ, pay = (ry + rowf) * CELLSZ;
            float paw = fabsf(rw), pah = fabsf(rh);
            float cx_rel = g.x * (float)S_GRID - colf;
            float cy_rel = g.y * (float)S_GRID - rowf;
            float gax = (cx_rel + colf) * CELLSZ;
            float gay = (cy_rel + rowf) * CELLSZ;
            float lcoord = ciou_fn(pax, pay, paw, pah, gax, gay, g.z, g.w);

            float dobj = rconf - best_iou;

            float lcls = 0.f;
#pragma unroll
            for (int k = 0; k < 10; ++k) {
                float tk = (mask >> k) & 1u ? 1.f : 0.f;
                lcls += focal_fn(P[10 + k], tk);
            }

            acc += 5.f * lcoord + dobj * dobj + 0.1f * (oconf * oconf) + lcls
                 - 0.1f * (conf0 * conf0 + conf1 * conf1);   // undo stream over-count
        }
    }

    // ---- block reduce -> partial ----
    for (int off = 32; off > 0; off >>= 1) acc += __shfl_down(acc, off);
    int lane = tid & 63, wid = tid >> 6;
    if (lane == 0) sred[wid] = acc;
    __syncthreads();
    if (tid == 0) {
        float s = 0.f;
#pragma unroll
        for (int w = 0; w < BLK / 64; ++w) s += sred[w];
        __hip_atomic_store(&partial[bid], s, __ATOMIC_RELEASE, __HIP_MEMORY_SCOPE_AGENT);
    }

    // ---- grid-wide barrier (execution + memory) ----
    cg::this_grid().sync();

    // ---- block 0: fixed-order final sum ----
    if (bid != 0) return;
    float facc = 0.f;
#pragma unroll
    for (int j = 0; j < GRID / BLK; ++j)   // 4 slots per thread, ascending
        facc += __hip_atomic_load(&partial[tid + j * BLK],
                                  __ATOMIC_ACQUIRE, __HIP_MEMORY_SCOPE_AGENT);
    for (int off = 32; off > 0; off >>= 1) facc += __shfl_down(facc, off);
    __syncthreads();                       // sred reuse safe
    if (lane == 0) sred[wid] = facc;
    __syncthreads();
    if (tid == 0) {
        float s = 0.f;
#pragma unroll
        for (int w = 0; w < BLK / 64; ++w) s += sred[w];
        out[0] = s / (float)BATCH_N;
    }
}

// ---------- launcher: ONE cooperative launch ----------

extern "C" void kernel_launch(void* const* d_in, const int* in_sizes, int n_in,
                              void* d_out, int out_size, void* d_ws, size_t ws_size,
                              hipStream_t stream) {
    const float* pred = (const float*)d_in[0];
    const float* tgt  = (const float*)d_in[1];
    float* partial = (float*)d_ws;          // GRID floats, fully rewritten every call
    float* out     = (float*)d_out;

    void* args[] = { (void*)&pred, (void*)&tgt, (void*)&partial, (void*)&out };
    hipLaunchCooperativeKernel(reinterpret_cast<void*>(fused_kernel),
                               dim3(GRID), dim3(BLK), args, 0, stream);
}

// Round 10
// 40.796 us; speedup vs baseline: 4.0198x; 4.0198x over previous
//
#include <hip/hip_runtime.h>
#include <math.h>

#define S_GRID   112
#define BATCH_N  64
#define NBOX     100
#define SS       (S_GRID * S_GRID)       // 12544 cells per image
#define NCELLS   (BATCH_N * SS)          // 802816
#define NF4      (NCELLS * 5)            // 4,014,080 float4s in pred
#define CELLSZ   (1.0f / (float)S_GRID)
#define BLK      256
#define GRID     2048
#define STRIDE   (GRID * BLK)            // 524288
#define FULL     7                       // NF4 / STRIDE
#define REM      (NF4 - FULL * STRIDE)   // 344064

// ---------- device helpers ----------

__device__ __forceinline__ float iou_fn(float px, float py, float pw, float ph,
                                        float gx, float gy, float gw, float gh) {
    // matches reference _iou (eps = 1e-6)
    float px1 = px - pw * 0.5f, px2 = px + pw * 0.5f;
    float py1 = py - ph * 0.5f, py2 = py + ph * 0.5f;
    float gx1 = gx - gw * 0.5f, gx2 = gx + gw * 0.5f;
    float gy1 = gy - gh * 0.5f, gy2 = gy + gh * 0.5f;
    float iw = fmaxf(fminf(px2, gx2) - fmaxf(px1, gx1), 0.f);
    float ih = fmaxf(fminf(py2, gy2) - fmaxf(py1, gy1), 0.f);
    float inter = iw * ih;
    float ap = fmaxf(px2 - px1, 0.f) * fmaxf(py2 - py1, 0.f);
    float ag = fmaxf(gx2 - gx1, 0.f) * fmaxf(gy2 - gy1, 0.f);
    float uni = ap + ag - inter;
    return inter / (uni + 1e-6f);
}

__device__ __forceinline__ float ciou_fn(float px, float py, float pw, float ph,
                                         float gx, float gy, float gw, float gh) {
    // matches reference _ciou (eps = 1e-7)
    const float eps = 1e-7f;
    float px1 = px - pw * 0.5f, px2 = px + pw * 0.5f;
    float py1 = py - ph * 0.5f, py2 = py + ph * 0.5f;
    float gx1 = gx - gw * 0.5f, gx2 = gx + gw * 0.5f;
    float gy1 = gy - gh * 0.5f, gy2 = gy + gh * 0.5f;
    float iw = fmaxf(fminf(px2, gx2) - fmaxf(px1, gx1), 0.f);
    float ih = fmaxf(fminf(py2, gy2) - fmaxf(py1, gy1), 0.f);
    float inter = iw * ih;
    float ap = fmaxf(px2 - px1, 0.f) * fmaxf(py2 - py1, 0.f);
    float ag = fmaxf(gx2 - gx1, 0.f) * fmaxf(gy2 - gy1, 0.f);
    float uni = ap + ag - inter;
    float iou = inter / (uni + eps);
    float dx = px - gx, dy = py - gy;
    float rho2 = dx * dx + dy * dy;
    float cw = fmaxf(px2, gx2) - fminf(px1, gx1);
    float ch = fmaxf(py2, gy2) - fminf(py1, gy1);
    float c2 = cw * cw + ch * ch + eps;
    float dv = atanf(gw / (gh + eps)) - atanf(pw / (ph + eps));
    float v = 0.40528473456935109f * dv * dv;   // 4/pi^2
    float alpha = v / (1.f - iou + v + eps);
    return 1.f - iou + rho2 / c2 + alpha * v;
}

__device__ __forceinline__ float focal_fn(float logit, float t) {
    float bce = fmaxf(logit, 0.f) - logit * t + log1pf(expf(-fabsf(logit)));
    float p = 1.f / (1.f + expf(-logit));
    float p_t = t * p + (1.f - t) * (1.f - p);
    float a_t = t * 0.25f + (1.f - t) * 0.75f;
    float om = 1.f - p_t;
    return a_t * om * om * bce;
}

// ---------- kernel 1: fused stream + hit ----------
// Phase A: all 2048 blocks stream pred (float4) for the 0.1*conf^2 noobj sum.
// Phase B: blocks 0..63 additionally handle image bid's hit cells (winner
//          scan, CIoU, focal, obj MSE, minus the stream's over-count).
// One partial per block; no workspace state, no atomics, no grid sync.

__global__ __launch_bounds__(BLK) void fused_kernel(const float* __restrict__ pred,
                                                    const float* __restrict__ tgt,
                                                    float* __restrict__ partial) {
    __shared__ int      s_cell[NBOX];
    __shared__ float4   s_box[NBOX];
    __shared__ unsigned s_cbit[NBOX];
    __shared__ float    sred[BLK / 64];

    const int bid = blockIdx.x, tid = threadIdx.x;
    const int gid = bid * BLK + tid;

    // ---- table build for hit blocks (block-uniform branch) ----
    if (bid < BATCH_N) {
        if (tid < NBOX) {
            const float* t = tgt + ((size_t)bid * NBOX + tid) * 5;
            float t0 = t[0], cx = t[1], cy = t[2], w = t[3], h = t[4];
            int cellid = -1; unsigned cb = 0u;
            if (t0 >= 0.f) {
                int cls = min(max((int)t0, 0), 9);
                int col = min(max((int)(cx * (float)S_GRID), 0), S_GRID - 1);
                int row = min(max((int)(cy * (float)S_GRID), 0), S_GRID - 1);
                cellid = row * S_GRID + col;
                cb = 1u << cls;
            }
            s_cell[tid] = cellid;
            s_box[tid]  = make_float4(cx, cy, w, h);
            s_cbit[tid] = cb;
        }
        __syncthreads();
    }

    // ---- phase A: stream noobj conf^2 ----
    const float4* p4 = (const float4*)pred;
    float sacc = 0.f;
    int r = gid % 5;
#pragma unroll
    for (int j = 0; j < FULL; ++j) {
        float4 v = p4[gid + j * STRIDE];
        if (r == 1) sacc += v.x * v.x;     // conf0 (float 4 of cell)
        if (r == 2) sacc += v.y * v.y;     // conf1 (float 9 of cell)
        r += 3; if (r >= 5) r -= 5;        // STRIDE % 5 == 3
    }
    if (gid < REM) {
        float4 v = p4[gid + FULL * STRIDE];
        if (r == 1) sacc += v.x * v.x;
        if (r == 2) sacc += v.y * v.y;
    }
    float acc = 0.1f * sacc;

    // ---- phase B: hit cells for image bid (blocks 0..63) ----
    if (bid < BATCH_N) {
        int mycell = (tid < NBOX) ? s_cell[tid] : -1;
        bool claim = (mycell >= 0);
        if (claim) {                      // owner = smallest box index for this cell
            for (int j = 0; j < tid; ++j)
                if (s_cell[j] == mycell) { claim = false; break; }
        }
        if (claim) {
            const int rc = mycell;
            const float colf = (float)(rc % S_GRID);
            const float rowf = (float)(rc / S_GRID);
            const float* P = pred + ((size_t)bid * SS + rc) * 20;

            float p0 = P[0], p1 = P[1], p2 = P[2], p3 = P[3], conf0 = P[4];
            float p5 = P[5], p6 = P[6], p7 = P[7], p8 = P[8], conf1 = P[9];

            float dx0 = (p0 + colf) * CELLSZ, dy0 = (p1 + rowf) * CELLSZ;
            float dx1 = (p5 + colf) * CELLSZ, dy1 = (p6 + rowf) * CELLSZ;

            unsigned mask = 0u; float bestv = -1.f; int jwin = 0, bj = 0;
            for (int j = 0; j < NBOX; ++j) {
                if (s_cell[j] == rc) {
                    mask |= s_cbit[j];
                    float4 g = s_box[j];
                    float i0 = iou_fn(dx0, dy0, p2, p3, g.x, g.y, g.z, g.w);
                    float i1 = iou_fn(dx1, dy1, p7, p8, g.x, g.y, g.z, g.w);
                    float b = fmaxf(i0, i1);
                    if (b > bestv) { bestv = b; jwin = j; bj = (i0 >= i1) ? 0 : 1; }
                }
            }

            float4 g = s_box[jwin];
            float best_iou = bestv;

            float rx = bj ? p5 : p0;
            float ry = bj ? p6 : p1;
            float rw = bj ? p7 : p2;
            float rh = bj ? p8 : p3;
            float rconf = bj ? conf1 : conf0;
            float oconf = bj ? conf0 : conf1;

            float pax = (rx + colf) * CELLSZ, pay = (ry + rowf) * CELLSZ;
            float paw = fabsf(rw), pah = fabsf(rh);
            float cx_rel = g.x * (float)S_GRID - colf;
            float cy_rel = g.y * (float)S_GRID - rowf;
            float gax = (cx_rel + colf) * CELLSZ;
            float gay = (cy_rel + rowf) * CELLSZ;
            float lcoord = ciou_fn(pax, pay, paw, pah, gax, gay, g.z, g.w);

            float dobj = rconf - best_iou;

            float lcls = 0.f;
#pragma unroll
            for (int k = 0; k < 10; ++k) {
                float tk = (mask >> k) & 1u ? 1.f : 0.f;
                lcls += focal_fn(P[10 + k], tk);
            }

            acc += 5.f * lcoord + dobj * dobj + 0.1f * (oconf * oconf) + lcls
                 - 0.1f * (conf0 * conf0 + conf1 * conf1);   // undo stream over-count
        }
    }

    // ---- block reduce -> partial ----
    for (int off = 32; off > 0; off >>= 1) acc += __shfl_down(acc, off);
    int lane = tid & 63, wid = tid >> 6;
    if (lane == 0) sred[wid] = acc;
    __syncthreads();
    if (tid == 0) {
        float s = 0.f;
#pragma unroll
        for (int w = 0; w < BLK / 64; ++w) s += sred[w];
        partial[bid] = s;
    }
}

// ---------- kernel 2: final reduction (fixed order, deterministic) ----------

__global__ __launch_bounds__(BLK) void reduce_kernel(const float* __restrict__ partial,
                                                     float* __restrict__ out) {
    float acc = 0.f;
#pragma unroll
    for (int j = 0; j < GRID / BLK; ++j)   // 8 slots per thread, ascending
        acc += partial[threadIdx.x + j * BLK];
    for (int off = 32; off > 0; off >>= 1) acc += __shfl_down(acc, off);
    __shared__ float sred[BLK / 64];
    int lane = threadIdx.x & 63, wid = threadIdx.x >> 6;
    if (lane == 0) sred[wid] = acc;
    __syncthreads();
    if (threadIdx.x == 0) {
        float s = 0.f;
#pragma unroll
        for (int w = 0; w < BLK / 64; ++w) s += sred[w];
        out[0] = s / (float)BATCH_N;
    }
}

// ---------- launcher: TWO launches ----------

extern "C" void kernel_launch(void* const* d_in, const int* in_sizes, int n_in,
                              void* d_out, int out_size, void* d_ws, size_t ws_size,
                              hipStream_t stream) {
    const float* pred = (const float*)d_in[0];
    const float* tgt  = (const float*)d_in[1];
    float* partial = (float*)d_ws;   // GRID floats, fully rewritten every call

    fused_kernel<<<GRID, BLK, 0, stream>>>(pred, tgt, partial);
    reduce_kernel<<<1, BLK, 0, stream>>>(partial, (float*)d_out);
}

// Round 11
// 35.362 us; speedup vs baseline: 4.6376x; 1.1537x over previous
//
#include <hip/hip_runtime.h>
#include <math.h>

#define S_GRID   112
#define BATCH_N  64
#define NBOX     100
#define SS       (S_GRID * S_GRID)       // 12544 cells per image
#define NCELLS   (BATCH_N * SS)          // 802816
#define NF4      (NCELLS * 5)            // 4,014,080 float4s in pred
#define CELLSZ   (1.0f / (float)S_GRID)
#define BLK      256
#define GRID     4096
#define NT       (GRID * BLK)            // 1,048,576 threads; NT % 5 == 1
#define REM3     (NF4 - 3 * NT)          // 868,352: threads with a 4th element

// ---------- device helpers ----------

__device__ __forceinline__ float iou_fn(float px, float py, float pw, float ph,
                                        float gx, float gy, float gw, float gh) {
    // matches reference _iou (eps = 1e-6)
    float px1 = px - pw * 0.5f, px2 = px + pw * 0.5f;
    float py1 = py - ph * 0.5f, py2 = py + ph * 0.5f;
    float gx1 = gx - gw * 0.5f, gx2 = gx + gw * 0.5f;
    float gy1 = gy - gh * 0.5f, gy2 = gy + gh * 0.5f;
    float iw = fmaxf(fminf(px2, gx2) - fmaxf(px1, gx1), 0.f);
    float ih = fmaxf(fminf(py2, gy2) - fmaxf(py1, gy1), 0.f);
    float inter = iw * ih;
    float ap = fmaxf(px2 - px1, 0.f) * fmaxf(py2 - py1, 0.f);
    float ag = fmaxf(gx2 - gx1, 0.f) * fmaxf(gy2 - gy1, 0.f);
    float uni = ap + ag - inter;
    return inter / (uni + 1e-6f);
}

__device__ __forceinline__ float ciou_fn(float px, float py, float pw, float ph,
                                         float gx, float gy, float gw, float gh) {
    // matches reference _ciou (eps = 1e-7)
    const float eps = 1e-7f;
    float px1 = px - pw * 0.5f, px2 = px + pw * 0.5f;
    float py1 = py - ph * 0.5f, py2 = py + ph * 0.5f;
    float gx1 = gx - gw * 0.5f, gx2 = gx + gw * 0.5f;
    float gy1 = gy - gh * 0.5f, gy2 = gy + gh * 0.5f;
    float iw = fmaxf(fminf(px2, gx2) - fmaxf(px1, gx1), 0.f);
    float ih = fmaxf(fminf(py2, gy2) - fmaxf(py1, gy1), 0.f);
    float inter = iw * ih;
    float ap = fmaxf(px2 - px1, 0.f) * fmaxf(py2 - py1, 0.f);
    float ag = fmaxf(gx2 - gx1, 0.f) * fmaxf(gy2 - gy1, 0.f);
    float uni = ap + ag - inter;
    float iou = inter / (uni + eps);
    float dx = px - gx, dy = py - gy;
    float rho2 = dx * dx + dy * dy;
    float cw = fmaxf(px2, gx2) - fminf(px1, gx1);
    float ch = fmaxf(py2, gy2) - fminf(py1, gy1);
    float c2 = cw * cw + ch * ch + eps;
    float dv = atanf(gw / (gh + eps)) - atanf(pw / (ph + eps));
    float v = 0.40528473456935109f * dv * dv;   // 4/pi^2
    float alpha = v / (1.f - iou + v + eps);
    return 1.f - iou + rho2 / c2 + alpha * v;
}

__device__ __forceinline__ float focal_fn(float logit, float t) {
    float bce = fmaxf(logit, 0.f) - logit * t + log1pf(expf(-fabsf(logit)));
    float p = 1.f / (1.f + expf(-logit));
    float p_t = t * p + (1.f - t) * (1.f - p);
    float a_t = t * 0.25f + (1.f - t) * 0.75f;
    float om = 1.f - p_t;
    return a_t * om * om * bce;
}

// ---------- kernel 1: fused stream (max MLP) + hit ----------
// Phase A: 4 NAMED independent float4 loads per thread issued before any
//          consume (forces >=4 loads in flight per wave; R10's VGPR=28 showed
//          the compiler kept ~1). Tail handled by clamped-address + zeroing.
// Phase B: blocks 0..63 handle image bid's hit cells (validated R7/R9/R10).

__global__ __launch_bounds__(BLK) void fused_kernel(const float* __restrict__ pred,
                                                    const float* __restrict__ tgt,
                                                    float* __restrict__ partial) {
    __shared__ int      s_cell[NBOX];
    __shared__ float4   s_box[NBOX];
    __shared__ unsigned s_cbit[NBOX];
    __shared__ float    sred[BLK / 64];

    const int bid = blockIdx.x, tid = threadIdx.x;
    const int gid = bid * BLK + tid;

    // ---- table build for hit blocks (block-uniform branch) ----
    if (bid < BATCH_N) {
        if (tid < NBOX) {
            const float* t = tgt + ((size_t)bid * NBOX + tid) * 5;
            float t0 = t[0], cx = t[1], cy = t[2], w = t[3], h = t[4];
            int cellid = -1; unsigned cb = 0u;
            if (t0 >= 0.f) {
                int cls = min(max((int)t0, 0), 9);
                int col = min(max((int)(cx * (float)S_GRID), 0), S_GRID - 1);
                int row = min(max((int)(cy * (float)S_GRID), 0), S_GRID - 1);
                cellid = row * S_GRID + col;
                cb = 1u << cls;
            }
            s_cell[tid] = cellid;
            s_box[tid]  = make_float4(cx, cy, w, h);
            s_cbit[tid] = cb;
        }
        __syncthreads();
    }

    // ---- phase A: 4 independent loads in flight, then consume ----
    const float4* p4 = (const float4*)pred;
    const bool has3 = (gid < REM3);
    const int  i3   = gid + (has3 ? 3 * NT : 0);   // clamped: always a valid addr

    float4 v0 = p4[gid];
    float4 v1 = p4[gid + NT];
    float4 v2 = p4[gid + 2 * NT];
    float4 v3 = p4[i3];

    // slot r of cell = idx % 5; conf0 = slot1.x, conf1 = slot2.y; NT % 5 == 1
    int r0 = gid % 5;
    int r1 = r0 + 1; if (r1 >= 5) r1 -= 5;
    int r2 = r1 + 1; if (r2 >= 5) r2 -= 5;
    int r3 = r2 + 1; if (r3 >= 5) r3 -= 5;

    float sacc = 0.f;
    sacc += (r0 == 1) ? v0.x * v0.x : 0.f;
    sacc += (r0 == 2) ? v0.y * v0.y : 0.f;
    sacc += (r1 == 1) ? v1.x * v1.x : 0.f;
    sacc += (r1 == 2) ? v1.y * v1.y : 0.f;
    sacc += (r2 == 1) ? v2.x * v2.x : 0.f;
    sacc += (r2 == 2) ? v2.y * v2.y : 0.f;
    sacc += (has3 && r3 == 1) ? v3.x * v3.x : 0.f;
    sacc += (has3 && r3 == 2) ? v3.y * v3.y : 0.f;
    float acc = 0.1f * sacc;

    // ---- phase B: hit cells for image bid (blocks 0..63) ----
    if (bid < BATCH_N) {
        int mycell = (tid < NBOX) ? s_cell[tid] : -1;
        bool claim = (mycell >= 0);
        if (claim) {                      // owner = smallest box index for this cell
            for (int j = 0; j < tid; ++j)
                if (s_cell[j] == mycell) { claim = false; break; }
        }
        if (claim) {
            const int rc = mycell;
            const float colf = (float)(rc % S_GRID);
            const float rowf = (float)(rc / S_GRID);
            const float* P = pred + ((size_t)bid * SS + rc) * 20;

            float p0 = P[0], p1 = P[1], p2 = P[2], p3 = P[3], conf0 = P[4];
            float p5 = P[5], p6 = P[6], p7 = P[7], p8 = P[8], conf1 = P[9];

            float dx0 = (p0 + colf) * CELLSZ, dy0 = (p1 + rowf) * CELLSZ;
            float dx1 = (p5 + colf) * CELLSZ, dy1 = (p6 + rowf) * CELLSZ;

            unsigned mask = 0u; float bestv = -1.f; int jwin = 0, bj = 0;
            for (int j = 0; j < NBOX; ++j) {
                if (s_cell[j] == rc) {
                    mask |= s_cbit[j];
                    float4 g = s_box[j];
                    float i0 = iou_fn(dx0, dy0, p2, p3, g.x, g.y, g.z, g.w);
                    float i1 = iou_fn(dx1, dy1, p7, p8, g.x, g.y, g.z, g.w);
                    float b = fmaxf(i0, i1);
                    if (b > bestv) { bestv = b; jwin = j; bj = (i0 >= i1) ? 0 : 1; }
                }
            }

            float4 g = s_box[jwin];
            float best_iou = bestv;

            float rx = bj ? p5 : p0;
            float ry = bj ? p6 : p1;
            float rw = bj ? p7 : p2;
            float rh = bj ? p8 : p3;
            float rconf = bj ? conf1 : conf0;
            float oconf = bj ? conf0 : conf1;

            float pax = (rx + colf) * CELLSZ, pay = (ry + rowf) * CELLSZ;
            float paw = fabsf(rw), pah = fabsf(rh);
            float cx_rel = g.x * (float)S_GRID - colf;
            float cy_rel = g.y * (float)S_GRID - rowf;
            float gax = (cx_rel + colf) * CELLSZ;
            float gay = (cy_rel + rowf) * CELLSZ;
            float lcoord = ciou_fn(pax, pay, paw, pah, gax, gay, g.z, g.w);

            float dobj = rconf - best_iou;

            float lcls = 0.f;
#pragma unroll
            for (int k = 0; k < 10; ++k) {
                float tk = (mask >> k) & 1u ? 1.f : 0.f;
                lcls += focal_fn(P[10 + k], tk);
            }

            acc += 5.f * lcoord + dobj * dobj + 0.1f * (oconf * oconf) + lcls
                 - 0.1f * (conf0 * conf0 + conf1 * conf1);   // undo stream over-count
        }
    }

    // ---- block reduce -> partial ----
    for (int off = 32; off > 0; off >>= 1) acc += __shfl_down(acc, off);
    int lane = tid & 63, wid = tid >> 6;
    if (lane == 0) sred[wid] = acc;
    __syncthreads();
    if (tid == 0) {
        float s = 0.f;
#pragma unroll
        for (int w = 0; w < BLK / 64; ++w) s += sred[w];
        partial[bid] = s;
    }
}

// ---------- kernel 2: final reduction (fixed order, deterministic) ----------

__global__ __launch_bounds__(BLK) void reduce_kernel(const float* __restrict__ partial,
                                                     float* __restrict__ out) {
    float acc = 0.f;
#pragma unroll
    for (int j = 0; j < GRID / BLK; ++j)   // 16 slots per thread, ascending
        acc += partial[threadIdx.x + j * BLK];
    for (int off = 32; off > 0; off >>= 1) acc += __shfl_down(acc, off);
    __shared__ float sred[BLK / 64];
    int lane = threadIdx.x & 63, wid = threadIdx.x >> 6;
    if (lane == 0) sred[wid] = acc;
    __syncthreads();
    if (threadIdx.x == 0) {
        float s = 0.f;
#pragma unroll
        for (int w = 0; w < BLK / 64; ++w) s += sred[w];
        out[0] = s / (float)BATCH_N;
    }
}

// ---------- launcher: TWO launches ----------

extern "C" void kernel_launch(void* const* d_in, const int* in_sizes, int n_in,
                              void* d_out, int out_size, void* d_ws, size_t ws_size,
                              hipStream_t stream) {
    const float* pred = (const float*)d_in[0];
    const float* tgt  = (const float*)d_in[1];
    float* partial = (float*)d_ws;   // GRID floats, fully rewritten every call

    fused_kernel<<<GRID, BLK, 0, stream>>>(pred, tgt, partial);
    reduce_kernel<<<1, BLK, 0, stream>>>(partial, (float*)d_out);
}

// Round 12
// 31.613 us; speedup vs baseline: 5.1874x; 1.1186x over previous
//
#include <hip/hip_runtime.h>
#include <math.h>

typedef unsigned long long ull;

#define S_GRID   112
#define BATCH_N  64
#define NBOX     100
#define SS       (S_GRID * S_GRID)       // 12544 cells per image
#define NCELLS   (BATCH_N * SS)          // 802816
#define NF4      (NCELLS * 5)            // 4,014,080 float4s in pred
#define CELLSZ   (1.0f / (float)S_GRID)
#define BLK      256
#define SGRID_B  2048                    // streaming blocks
#define HIT_BASE SGRID_B                 // hit blocks: 2048..2111
#define GRID_TOT (SGRID_B + BATCH_N)     // 2112
#define NT       (SGRID_B * BLK)         // 524288 streaming threads; NT % 5 == 3
#define FULL     7                       // full chunks per thread
#define REM      (NF4 - FULL * NT)       // 344064 threads take an 8th element

// ---------- device helpers ----------

__device__ __forceinline__ float iou_fn(float px, float py, float pw, float ph,
                                        float gx, float gy, float gw, float gh) {
    // matches reference _iou (eps = 1e-6)
    float px1 = px - pw * 0.5f, px2 = px + pw * 0.5f;
    float py1 = py - ph * 0.5f, py2 = py + ph * 0.5f;
    float gx1 = gx - gw * 0.5f, gx2 = gx + gw * 0.5f;
    float gy1 = gy - gh * 0.5f, gy2 = gy + gh * 0.5f;
    float iw = fmaxf(fminf(px2, gx2) - fmaxf(px1, gx1), 0.f);
    float ih = fmaxf(fminf(py2, gy2) - fmaxf(py1, gy1), 0.f);
    float inter = iw * ih;
    float ap = fmaxf(px2 - px1, 0.f) * fmaxf(py2 - py1, 0.f);
    float ag = fmaxf(gx2 - gx1, 0.f) * fmaxf(gy2 - gy1, 0.f);
    float uni = ap + ag - inter;
    return inter / (uni + 1e-6f);
}

__device__ __forceinline__ float ciou_fn(float px, float py, float pw, float ph,
                                         float gx, float gy, float gw, float gh) {
    // matches reference _ciou (eps = 1e-7)
    const float eps = 1e-7f;
    float px1 = px - pw * 0.5f, px2 = px + pw * 0.5f;
    float py1 = py - ph * 0.5f, py2 = py + ph * 0.5f;
    float gx1 = gx - gw * 0.5f, gx2 = gx + gw * 0.5f;
    float gy1 = gy - gh * 0.5f, gy2 = gy + gh * 0.5f;
    float iw = fmaxf(fminf(px2, gx2) - fmaxf(px1, gx1), 0.f);
    float ih = fmaxf(fminf(py2, gy2) - fmaxf(py1, gy1), 0.f);
    float inter = iw * ih;
    float ap = fmaxf(px2 - px1, 0.f) * fmaxf(py2 - py1, 0.f);
    float ag = fmaxf(gx2 - gx1, 0.f) * fmaxf(gy2 - gy1, 0.f);
    float uni = ap + ag - inter;
    float iou = inter / (uni + eps);
    float dx = px - gx, dy = py - gy;
    float rho2 = dx * dx + dy * dy;
    float cw = fmaxf(px2, gx2) - fminf(px1, gx1);
    float ch = fmaxf(py2, gy2) - fminf(py1, gy1);
    float c2 = cw * cw + ch * ch + eps;
    float dv = atanf(gw / (gh + eps)) - atanf(pw / (ph + eps));
    float v = 0.40528473456935109f * dv * dv;   // 4/pi^2
    float alpha = v / (1.f - iou + v + eps);
    return 1.f - iou + rho2 / c2 + alpha * v;
}

__device__ __forceinline__ float focal_fn(float logit, float t) {
    float bce = fmaxf(logit, 0.f) - logit * t + log1pf(expf(-fabsf(logit)));
    float p = 1.f / (1.f + expf(-logit));
    float p_t = t * p + (1.f - t) * (1.f - p);
    float a_t = t * 0.25f + (1.f - t) * 0.75f;
    float om = 1.f - p_t;
    return a_t * om * om * bce;
}

// ---------- kernel 1: stream blocks (0..2047) + hit blocks (2048..2111) ----------
// Stream: 8 NAMED independent float4 loads in flight per thread.
// Hit: per-box-parallel winner selection via LDS u64 atomicMax
//      (key = iou_bits<<32 | (NBOX-t)<<1 | bj  -> max iou, then smallest t),
//      then one CIoU+focal per owning (cell-representative) thread.

__global__ __launch_bounds__(BLK) void fused_kernel(const float* __restrict__ pred,
                                                    const float* __restrict__ tgt,
                                                    float* __restrict__ partial) {
    __shared__ int      s_cell[NBOX];
    __shared__ float4   s_box[NBOX];
    __shared__ unsigned s_cbit[NBOX];
    __shared__ ull      s_key[NBOX];
    __shared__ unsigned s_mask[NBOX];
    __shared__ float    sred[BLK / 64];

    const int bid = blockIdx.x, tid = threadIdx.x;
    float acc = 0.f;

    if (bid < SGRID_B) {
        // ================= streaming path =================
        const int gid = bid * BLK + tid;
        const float4* p4 = (const float4*)pred;
        const bool has7 = (gid < REM);
        const int  i7   = gid + (has7 ? FULL * NT : 0);   // clamped valid addr

        float4 v0 = p4[gid];
        float4 v1 = p4[gid + NT];
        float4 v2 = p4[gid + 2 * NT];
        float4 v3 = p4[gid + 3 * NT];
        float4 v4 = p4[gid + 4 * NT];
        float4 v5 = p4[gid + 5 * NT];
        float4 v6 = p4[gid + 6 * NT];
        float4 v7 = p4[i7];

        float sacc = 0.f;
        int r = gid % 5;                    // slot within cell; conf0=slot1.x, conf1=slot2.y
#define ACC(v) { if (r == 1) sacc += v.x * v.x; if (r == 2) sacc += v.y * v.y; \
                 r += 3; if (r >= 5) r -= 5; }   // NT % 5 == 3
        ACC(v0) ACC(v1) ACC(v2) ACC(v3) ACC(v4) ACC(v5) ACC(v6)
#undef ACC
        if (has7) {
            if (r == 1) sacc += v7.x * v7.x;
            if (r == 2) sacc += v7.y * v7.y;
        }
        acc = 0.1f * sacc;
    } else {
        // ================= hit path (one block per image) =================
        const int img = bid - HIT_BASE;

        if (tid < NBOX) {
            const float* t = tgt + ((size_t)img * NBOX + tid) * 5;
            float t0 = t[0], cx = t[1], cy = t[2], w = t[3], h = t[4];
            int cellid = -1; unsigned cb = 0u;
            if (t0 >= 0.f) {
                int cls = min(max((int)t0, 0), 9);
                int col = min(max((int)(cx * (float)S_GRID), 0), S_GRID - 1);
                int row = min(max((int)(cy * (float)S_GRID), 0), S_GRID - 1);
                cellid = row * S_GRID + col;
                cb = 1u << cls;
            }
            s_cell[tid] = cellid;
            s_box[tid]  = make_float4(cx, cy, w, h);
            s_cbit[tid] = cb;
            s_key[tid]  = 0ull;
            s_mask[tid] = 0u;
        }
        __syncthreads();

        int mycell = (tid < NBOX) ? s_cell[tid] : -1;
        int owner = tid;
        float4 pa, pb; float pc8 = 0.f, pc9 = 0.f;
        float colf = 0.f, rowf = 0.f;

        // step 1: per-box iou vs its own cell's two pred boxes
        if (mycell >= 0) {
            for (int j = 0; j < tid; ++j)
                if (s_cell[j] == mycell) { owner = j; break; }
            colf = (float)(mycell % S_GRID);
            rowf = (float)(mycell / S_GRID);
            const float* P = pred + ((size_t)img * SS + mycell) * 20;
            pa  = *(const float4*)P;        // p0 p1 p2 p3
            pb  = *(const float4*)(P + 4);  // conf0 p5 p6 p7
            pc8 = P[8]; pc9 = P[9];         // p8, conf1
            float4 g = s_box[tid];
            float dx0 = (pa.x + colf) * CELLSZ, dy0 = (pa.y + rowf) * CELLSZ;
            float i0 = iou_fn(dx0, dy0, pa.z, pa.w, g.x, g.y, g.z, g.w);
            float dx1 = (pb.y + colf) * CELLSZ, dy1 = (pb.z + rowf) * CELLSZ;
            float i1 = iou_fn(dx1, dy1, pb.w, pc8, g.x, g.y, g.z, g.w);
            float b = fmaxf(i0, i1);
            int bj = (i0 >= i1) ? 0 : 1;
            ull key = ((ull)__float_as_uint(b) << 32)
                    | (ull)((((unsigned)(NBOX - tid)) << 1) | (unsigned)bj);
            atomicMax(&s_key[owner], key);
            atomicOr(&s_mask[owner], s_cbit[tid]);
        }
        __syncthreads();

        // step 2: cell representatives compute the per-cell loss
        if (mycell >= 0 && owner == tid) {
            ull key = s_key[tid];
            float best_iou = __uint_as_float((unsigned)(key >> 32));
            unsigned lo = (unsigned)key;
            int bjw = (int)(lo & 1u);
            int m   = NBOX - (int)(lo >> 1);
            float4 g = s_box[m];
            unsigned mask = s_mask[tid];

            float conf0 = pb.x, conf1 = pc9;
            float rx = bjw ? pb.y : pa.x;
            float ry = bjw ? pb.z : pa.y;
            float rw = bjw ? pb.w : pa.z;
            float rh = bjw ? pc8  : pa.w;
            float rconf = bjw ? conf1 : conf0;
            float oconf = bjw ? conf0 : conf1;

            float pax = (rx + colf) * CELLSZ, pay = (ry + rowf) * CELLSZ;
            float paw = fabsf(rw), pah = fabsf(rh);
            float cx_rel = g.x * (float)S_GRID - colf;
            float cy_rel = g.y * (float)S_GRID - rowf;
            float gax = (cx_rel + colf) * CELLSZ;
            float gay = (cy_rel + rowf) * CELLSZ;
            float lcoord = ciou_fn(pax, pay, paw, pah, gax, gay, g.z, g.w);

            float dobj = rconf - best_iou;

            const float* P = pred + ((size_t)img * SS + mycell) * 20;
            float lcls = 0.f;
#pragma unroll
            for (int k = 0; k < 10; ++k) {
                float tk = (mask >> k) & 1u ? 1.f : 0.f;
                lcls += focal_fn(P[10 + k], tk);
            }

            acc = 5.f * lcoord + dobj * dobj + 0.1f * (oconf * oconf) + lcls
                - 0.1f * (conf0 * conf0 + conf1 * conf1);   // undo stream over-count
        }
    }

    // ---- block reduce -> partial (both paths) ----
    for (int off = 32; off > 0; off >>= 1) acc += __shfl_down(acc, off);
    int lane = tid & 63, wid = tid >> 6;
    if (lane == 0) sred[wid] = acc;
    __syncthreads();
    if (tid == 0) {
        float s = 0.f;
#pragma unroll
        for (int w = 0; w < BLK / 64; ++w) s += sred[w];
        partial[bid] = s;
    }
}

// ---------- kernel 2: final reduction (fixed order, deterministic) ----------

__global__ __launch_bounds__(BLK) void reduce_kernel(const float* __restrict__ partial,
                                                     float* __restrict__ out) {
    float acc = 0.f;
#pragma unroll
    for (int j = 0; j < SGRID_B / BLK; ++j)          // 8 stream slots per thread
        acc += partial[threadIdx.x + j * BLK];
    if (threadIdx.x < BATCH_N)                       // hit-block slots
        acc += partial[HIT_BASE + threadIdx.x];
    for (int off = 32; off > 0; off >>= 1) acc += __shfl_down(acc, off);
    __shared__ float sred[BLK / 64];
    int lane = threadIdx.x & 63, wid = threadIdx.x >> 6;
    if (lane == 0) sred[wid] = acc;
    __syncthreads();
    if (threadIdx.x == 0) {
        float s = 0.f;
#pragma unroll
        for (int w = 0; w < BLK / 64; ++w) s += sred[w];
        out[0] = s / (float)BATCH_N;
    }
}

// ---------- launcher: TWO launches ----------

extern "C" void kernel_launch(void* const* d_in, const int* in_sizes, int n_in,
                              void* d_out, int out_size, void* d_ws, size_t ws_size,
                              hipStream_t stream) {
    const float* pred = (const float*)d_in[0];
    const float* tgt  = (const float*)d_in[1];
    float* partial = (float*)d_ws;   // GRID_TOT floats, fully rewritten every call

    fused_kernel<<<GRID_TOT, BLK, 0, stream>>>(pred, tgt, partial);
    reduce_kernel<<<1, BLK, 0, stream>>>(partial, (float*)d_out);
}